// Round 7
// baseline (48.361 us; speedup 1.0000x reference)
//
#include <hip/hip_runtime.h>
#include <hip/hip_fp16.h>

// SoftPixelCNN: out[v, o*64+f] = (1/K) * sum_k exp(-A*d[o,v,k]) * feats[nidx[v,k], f]
// d[o,v,k] = ||(c_v + off_o) - c_n||^2 = base + 2*delta.off_o + ||off_o||^2, A = 10*length_scale.
// Offsets (meshgrid-xy order): [0, -e1, -e0, -e2, -e3, +e3, +e2, +e0, +e1].
// NUMERICS: exponentiate the COMBINED exponent (always <= 0) -> no 0*inf NaN.
// r6: wave-uniform ballot skip of neighbours with maxarg < -15 (error << threshold).
// r7: features packed to f16 once per launch (12.8 -> 6.4 MB): gathered rows are 128 B
//     and the table ~fits per-XCD L2 -> random-miss fetch traffic drops ~3x.
//     Weights LDS is same-wave write->read, so no __syncthreads needed.

#define KNB 32
#define FDIM 64
#define ODIM 9

__global__ __launch_bounds__(256) void pack_f16(const float4* __restrict__ src,
                                                ushort4* __restrict__ dst, int n4) {
    int i = blockIdx.x * 256 + threadIdx.x;
    if (i < n4) {
        float4 v = src[i];
        ushort4 p;
        p.x = __half_as_ushort(__float2half(v.x));
        p.y = __half_as_ushort(__float2half(v.y));
        p.z = __half_as_ushort(__float2half(v.z));
        p.w = __half_as_ushort(__float2half(v.w));
        dst[i] = p;
    }
}

__global__ __launch_bounds__(256) void spcnn_kernel(
    const float*  __restrict__ coords,   // (V,4)
    const ushort* __restrict__ pf,       // (V,64) f16 bits (packed)
    const int*    __restrict__ nidx,     // (V,32)
    const float*  __restrict__ lscale,   // (1,)
    float*        __restrict__ out)      // (V,576)
{
    __shared__ float wlds[4][KNB][12];  // [warp][k][0..8] weights (stride 12: b128-aligned)
    const int warp = threadIdx.x >> 6;
    const int lane = threadIdx.x & 63;
    const int v = blockIdx.x * 4 + warp;

    const float A = 10.0f * lscale[0];
    const int myidx = nidx[v * KNB + (lane & 31)];   // lane L holds k = L&31

    // ---- phase 1 (all lanes): exponents for my k; ballot the keep-mask ----
    const float4 cn = *(const float4*)(coords + (size_t)(unsigned)myidx * 4);
    const float4 cv = *(const float4*)(coords + (size_t)v * 4);
    const float d0 = cv.x - cn.x, d1 = cv.y - cn.y, d2 = cv.z - cn.z, d3 = cv.w - cn.w;
    const float base = d0*d0 + d1*d1 + d2*d2 + d3*d3;

    const float ex = -A * base;                 // origin-offset exponent
    const float bm = ex - A;                    // minus A*||off||^2 (=1 for axis offsets)
    const float t0 = 2.f*A*d0, t1 = 2.f*A*d1, t2 = 2.f*A*d2, t3 = 2.f*A*d3;

    const float mt = fmaxf(fmaxf(fabsf(t0), fabsf(t1)), fmaxf(fabsf(t2), fabsf(t3)));
    const float maxarg = fmaxf(ex, bm + mt);    // exact max over the 9 exponents
    const unsigned long long keep = __ballot(maxarg >= -15.0f);  // wave-uniform SGPR mask

    if (lane < 32) {
        const float s = 1.0f / (float)KNB;      // fold mean-over-K
        const float w0 = __expf(ex)      * s;
        const float w1 = __expf(bm + t1) * s;   // o = -e1
        const float w2 = __expf(bm + t0) * s;   // o = -e0
        const float w3 = __expf(bm + t2) * s;   // o = -e2
        const float w4 = __expf(bm + t3) * s;   // o = -e3
        const float w5 = __expf(bm - t3) * s;   // o = +e3
        const float w6 = __expf(bm - t2) * s;   // o = +e2
        const float w7 = __expf(bm - t0) * s;   // o = +e0
        const float w8 = __expf(bm - t1) * s;   // o = +e1
        float* wp = wlds[warp][lane];
        *(float4*)(wp)     = make_float4(w0, w1, w2, w3);
        *(float4*)(wp + 4) = make_float4(w4, w5, w6, w7);
        wp[8] = w8;
    }
    // no __syncthreads: wlds[warp] is written and read by the SAME wave (DS in-order)

    // ---- phase 2: lane = feature f; only live neighbors touch memory/VALU ----
    float acc0=0.f,acc1=0.f,acc2=0.f,acc3=0.f,acc4=0.f,acc5=0.f,acc6=0.f,acc7=0.f,acc8=0.f;
    const float* wbase = wlds[warp][0];

    #pragma unroll
    for (int k = 0; k < KNB; ++k) {
        if (!((keep >> k) & 1ull)) continue;     // wave-uniform -> s_cbranch, no gather
        const float* wp = wbase + k * 12;
        const float4 wa = *(const float4*)wp;        // broadcast ds_read_b128
        const float4 wb = *(const float4*)(wp + 4);  // broadcast ds_read_b128
        const float w8 = wp[8];                      // broadcast ds_read_b32
        const unsigned idx = (unsigned)__builtin_amdgcn_readlane(myidx, k); // SGPR base
        const float gk = __half2float(__ushort_as_half(pf[(size_t)idx * FDIM + lane]));
        acc0 = fmaf(wa.x, gk, acc0); acc1 = fmaf(wa.y, gk, acc1);
        acc2 = fmaf(wa.z, gk, acc2); acc3 = fmaf(wa.w, gk, acc3);
        acc4 = fmaf(wb.x, gk, acc4); acc5 = fmaf(wb.y, gk, acc5);
        acc6 = fmaf(wb.z, gk, acc6); acc7 = fmaf(wb.w, gk, acc7);
        acc8 = fmaf(w8,  gk, acc8);
    }

    float* op = out + (size_t)v * (ODIM * FDIM) + lane;
    op[0*FDIM] = acc0; op[1*FDIM] = acc1; op[2*FDIM] = acc2;
    op[3*FDIM] = acc3; op[4*FDIM] = acc4; op[5*FDIM] = acc5;
    op[6*FDIM] = acc6; op[7*FDIM] = acc7; op[8*FDIM] = acc8;
}

extern "C" void kernel_launch(void* const* d_in, const int* in_sizes, int n_in,
                              void* d_out, int out_size, void* d_ws, size_t ws_size,
                              hipStream_t stream) {
    const float* coords = (const float*)d_in[0];   // (V,4) f32
    const float* feats  = (const float*)d_in[1];   // (V,64) f32
    // d_in[2] = distsq — unused on the inference path
    const int*   nbidx  = (const int*)d_in[3];     // (V,32) i32
    const float* lscale = (const float*)d_in[4];   // (1,) f32

    const int V  = in_sizes[0] / 4;                // 50000
    const int n4 = in_sizes[1] / 4;                // V*64/4 float4s

    ushort* pf = (ushort*)d_ws;                    // f16 feature table (V*64*2 B = 6.4 MB)
    pack_f16<<<(n4 + 255) / 256, 256, 0, stream>>>((const float4*)feats, (ushort4*)pf, n4);
    spcnn_kernel<<<V / 4, 256, 0, stream>>>(coords, pf, nbidx, lscale, (float*)d_out);
}

// Round 8
// 42.419 us; speedup vs baseline: 1.1401x; 1.1401x over previous
//
#include <hip/hip_runtime.h>

// SoftPixelCNN: out[v, o*64+f] = (1/K) * sum_k exp(-A*d[o,v,k]) * feats[nidx[v,k], f]
// d[o,v,k] = ||(c_v + off_o) - c_n||^2 = base + 2*delta.off_o + ||off_o||^2, A = 10*length_scale.
// Offsets (meshgrid-xy order): [0, -e1, -e0, -e2, -e3, +e3, +e2, +e0, +e1].
// NUMERICS: exponentiate the COMBINED exponent (always <= 0) -> no 0*inf NaN.
// r6: wave-uniform ballot skip of neighbours with maxarg < -15 (dropped weight < e^-15,
//     contribution < 5*e^-15 ~ 1.5e-6 per output vs threshold 2.3e-3).
// r8: iterate ONLY live neighbours via ctz on the wave-uniform mask (~3 iters, not 32
//     tests); weights broadcast from the computing lane's VGPRs via v_readlane with the
//     runtime k (no LDS at all); exps predicated on the keep bit. f32 table (no pack).

#define KNB 32
#define FDIM 64
#define ODIM 9

__global__ __launch_bounds__(256) void spcnn_kernel(
    const float* __restrict__ coords,   // (V,4)
    const float* __restrict__ feats,    // (V,64)
    const int*   __restrict__ nidx,     // (V,32)
    const float* __restrict__ lscale,   // (1,)
    float* __restrict__ out)            // (V,576)
{
    const int lane = threadIdx.x & 63;
    const int v = blockIdx.x * 4 + (threadIdx.x >> 6);

    const float A = 10.0f * lscale[0];
    const int myidx = nidx[v * KNB + (lane & 31)];   // lane L holds k = L&31

    // ---- phase 1 (all lanes, branchless): exponents for my k; ballot keep-mask ----
    const float4 cn = *(const float4*)(coords + (size_t)(unsigned)myidx * 4);
    const float4 cv = *(const float4*)(coords + (size_t)v * 4);
    const float d0 = cv.x - cn.x, d1 = cv.y - cn.y, d2 = cv.z - cn.z, d3 = cv.w - cn.w;
    const float base = d0*d0 + d1*d1 + d2*d2 + d3*d3;

    const float ex = -A * base;                 // origin-offset exponent
    const float bm = ex - A;                    // minus A*||off||^2 (=1 for axis offsets)
    const float t0 = 2.f*A*d0, t1 = 2.f*A*d1, t2 = 2.f*A*d2, t3 = 2.f*A*d3;

    const float mt = fmaxf(fmaxf(fabsf(t0), fabsf(t1)), fmaxf(fabsf(t2), fabsf(t3)));
    const float maxarg = fmaxf(ex, bm + mt);    // exact max over the 9 exponents
    const bool alive = (maxarg >= -15.0f);
    const unsigned long long keep64 = __ballot(alive);
    unsigned m = (unsigned)(keep64 & 0xFFFFFFFFull);   // bits 0..31 (high half mirrors)

    // weights for my k, only if some offset survives (dead lanes' regs never read)
    float w0 = 0.f, w1 = 0.f, w2 = 0.f, w3 = 0.f, w4 = 0.f,
          w5 = 0.f, w6 = 0.f, w7 = 0.f, w8 = 0.f;
    if (alive) {
        const float s = 1.0f / (float)KNB;      // fold mean-over-K
        w0 = __expf(ex)      * s;
        w1 = __expf(bm + t1) * s;               // o = -e1
        w2 = __expf(bm + t0) * s;               // o = -e0
        w3 = __expf(bm + t2) * s;               // o = -e2
        w4 = __expf(bm + t3) * s;               // o = -e3
        w5 = __expf(bm - t3) * s;               // o = +e3
        w6 = __expf(bm - t2) * s;               // o = +e2
        w7 = __expf(bm - t0) * s;               // o = +e0
        w8 = __expf(bm - t1) * s;               // o = +e1
    }

    // ---- phase 2: lane = feature f; scalar loop over live neighbours only ----
    float acc0=0.f,acc1=0.f,acc2=0.f,acc3=0.f,acc4=0.f,acc5=0.f,acc6=0.f,acc7=0.f,acc8=0.f;
    while (m) {
        const int k = __builtin_ctz(m);          // s_ff1 on wave-uniform mask
        m &= m - 1;
        const unsigned idx = (unsigned)__builtin_amdgcn_readlane(myidx, k); // SGPR base
        const float gk = feats[(size_t)idx * FDIM + lane];   // coalesced 256B row
        const float s0 = __int_as_float(__builtin_amdgcn_readlane(__float_as_int(w0), k));
        const float s1 = __int_as_float(__builtin_amdgcn_readlane(__float_as_int(w1), k));
        const float s2 = __int_as_float(__builtin_amdgcn_readlane(__float_as_int(w2), k));
        const float s3 = __int_as_float(__builtin_amdgcn_readlane(__float_as_int(w3), k));
        const float s4 = __int_as_float(__builtin_amdgcn_readlane(__float_as_int(w4), k));
        const float s5 = __int_as_float(__builtin_amdgcn_readlane(__float_as_int(w5), k));
        const float s6 = __int_as_float(__builtin_amdgcn_readlane(__float_as_int(w6), k));
        const float s7 = __int_as_float(__builtin_amdgcn_readlane(__float_as_int(w7), k));
        const float s8 = __int_as_float(__builtin_amdgcn_readlane(__float_as_int(w8), k));
        acc0 = fmaf(s0, gk, acc0); acc1 = fmaf(s1, gk, acc1); acc2 = fmaf(s2, gk, acc2);
        acc3 = fmaf(s3, gk, acc3); acc4 = fmaf(s4, gk, acc4); acc5 = fmaf(s5, gk, acc5);
        acc6 = fmaf(s6, gk, acc6); acc7 = fmaf(s7, gk, acc7); acc8 = fmaf(s8, gk, acc8);
    }

    float* op = out + (size_t)v * (ODIM * FDIM) + lane;
    op[0*FDIM] = acc0; op[1*FDIM] = acc1; op[2*FDIM] = acc2;
    op[3*FDIM] = acc3; op[4*FDIM] = acc4; op[5*FDIM] = acc5;
    op[6*FDIM] = acc6; op[7*FDIM] = acc7; op[8*FDIM] = acc8;
}

extern "C" void kernel_launch(void* const* d_in, const int* in_sizes, int n_in,
                              void* d_out, int out_size, void* d_ws, size_t ws_size,
                              hipStream_t stream) {
    const float* coords = (const float*)d_in[0];   // (V,4) f32
    const float* feats  = (const float*)d_in[1];   // (V,64) f32
    // d_in[2] = distsq — unused on the inference path
    const int*   nbidx  = (const int*)d_in[3];     // (V,32) i32
    const float* lscale = (const float*)d_in[4];   // (1,) f32

    const int V = in_sizes[0] / 4;                 // 50000
    spcnn_kernel<<<V / 4, 256, 0, stream>>>(coords, feats, nbidx, lscale, (float*)d_out);
}

// Round 9
// 41.723 us; speedup vs baseline: 1.1591x; 1.0167x over previous
//
#include <hip/hip_runtime.h>

// SoftPixelCNN: out[v, o*64+f] = (1/K) * sum_k exp(-A*d[o,v,k]) * feats[nidx[v,k], f]
// d[o,v,k] = ||(c_v + off_o) - c_n||^2, A = 10*length_scale.
// Offsets (meshgrid-xy order): [0, -e1, -e0, -e2, -e3, +e3, +e2, +e0, +e1].
// NUMERICS: exponentiate the COMBINED exponent (always <= 0) -> no 0*inf NaN.
// r6: wave-uniform ballot skip of neighbours with maxarg < -15 (error ~1.5e-6 << 2.3e-3).
// r9: TWO vertices per wave (lanes 0-31: v0, lanes 32-63: v1) -> one coalesced nidx load,
//     dense exp phase, merged 64-bit ctz loop, 2x memory-level parallelism per wave.
//     Nontemporal output stores keep the feature table resident in L2.

#define KNB 32
#define FDIM 64
#define ODIM 9

__global__ __launch_bounds__(256) void spcnn_kernel(
    const float* __restrict__ coords,   // (V,4)
    const float* __restrict__ feats,    // (V,64)
    const int*   __restrict__ nidx,     // (V,32)
    const float* __restrict__ lscale,   // (1,)
    float* __restrict__ out)            // (V,576)
{
    const int lane = threadIdx.x & 63;
    const int v0 = (blockIdx.x * 4 + (threadIdx.x >> 6)) * 2;  // wave owns v0, v0+1
    const int myv = v0 + (lane >> 5);                          // my half's vertex

    const float A = 10.0f * lscale[0];
    // one coalesced 256B load: rows of v0 and v1 are contiguous in nidx
    const int myidx = nidx[v0 * KNB + lane];

    // ---- phase 1 (all lanes useful): exponents for (myv, k=lane&31); 64-bit ballot ----
    const float4 cn = *(const float4*)(coords + (size_t)(unsigned)myidx * 4);
    const float4 cv = *(const float4*)(coords + (size_t)myv * 4);
    const float d0 = cv.x - cn.x, d1 = cv.y - cn.y, d2 = cv.z - cn.z, d3 = cv.w - cn.w;
    const float base = d0*d0 + d1*d1 + d2*d2 + d3*d3;

    const float ex = -A * base;                 // origin-offset exponent
    const float bm = ex - A;                    // minus A*||off||^2 (=1 for axis offsets)
    const float t0 = 2.f*A*d0, t1 = 2.f*A*d1, t2 = 2.f*A*d2, t3 = 2.f*A*d3;

    const float mt = fmaxf(fmaxf(fabsf(t0), fabsf(t1)), fmaxf(fabsf(t2), fabsf(t3)));
    const float maxarg = fmaxf(ex, bm + mt);    // exact max over the 9 exponents
    const bool alive = (maxarg >= -15.0f);
    unsigned long long m = __ballot(alive);     // low 32: v0's keep, high 32: v1's

    float w0=0.f,w1=0.f,w2=0.f,w3=0.f,w4=0.f,w5=0.f,w6=0.f,w7=0.f,w8=0.f;
    if (alive) {
        const float s = 1.0f / (float)KNB;      // fold mean-over-K
        w0 = __expf(ex)      * s;
        w1 = __expf(bm + t1) * s;               // o = -e1
        w2 = __expf(bm + t0) * s;               // o = -e0
        w3 = __expf(bm + t2) * s;               // o = -e2
        w4 = __expf(bm + t3) * s;               // o = -e3
        w5 = __expf(bm - t3) * s;               // o = +e3
        w6 = __expf(bm - t2) * s;               // o = +e2
        w7 = __expf(bm - t0) * s;               // o = +e0
        w8 = __expf(bm - t1) * s;               // o = +e1
    }

    // ---- phase 2: lane = feature f; merged scalar loop over both vertices' live k ----
    float a0=0.f,a1=0.f,a2=0.f,a3=0.f,a4=0.f,a5=0.f,a6=0.f,a7=0.f,a8=0.f;  // v0
    float b0=0.f,b1=0.f,b2=0.f,b3=0.f,b4=0.f,b5=0.f,b6=0.f,b7=0.f,b8=0.f;  // v1
    while (m) {
        const int k = __builtin_ctzll(m);        // s_ff1 on wave-uniform 64-bit mask
        m &= m - 1;
        const unsigned idx = (unsigned)__builtin_amdgcn_readlane(myidx, k); // SGPR base
        const float gk = feats[(size_t)idx * FDIM + lane];   // coalesced 256B row
        const float s0 = __int_as_float(__builtin_amdgcn_readlane(__float_as_int(w0), k));
        const float s1 = __int_as_float(__builtin_amdgcn_readlane(__float_as_int(w1), k));
        const float s2 = __int_as_float(__builtin_amdgcn_readlane(__float_as_int(w2), k));
        const float s3 = __int_as_float(__builtin_amdgcn_readlane(__float_as_int(w3), k));
        const float s4 = __int_as_float(__builtin_amdgcn_readlane(__float_as_int(w4), k));
        const float s5 = __int_as_float(__builtin_amdgcn_readlane(__float_as_int(w5), k));
        const float s6 = __int_as_float(__builtin_amdgcn_readlane(__float_as_int(w6), k));
        const float s7 = __int_as_float(__builtin_amdgcn_readlane(__float_as_int(w7), k));
        const float s8 = __int_as_float(__builtin_amdgcn_readlane(__float_as_int(w8), k));
        if (k < KNB) {   // wave-uniform branch: which vertex's accumulators
            a0 = fmaf(s0, gk, a0); a1 = fmaf(s1, gk, a1); a2 = fmaf(s2, gk, a2);
            a3 = fmaf(s3, gk, a3); a4 = fmaf(s4, gk, a4); a5 = fmaf(s5, gk, a5);
            a6 = fmaf(s6, gk, a6); a7 = fmaf(s7, gk, a7); a8 = fmaf(s8, gk, a8);
        } else {
            b0 = fmaf(s0, gk, b0); b1 = fmaf(s1, gk, b1); b2 = fmaf(s2, gk, b2);
            b3 = fmaf(s3, gk, b3); b4 = fmaf(s4, gk, b4); b5 = fmaf(s5, gk, b5);
            b6 = fmaf(s6, gk, b6); b7 = fmaf(s7, gk, b7); b8 = fmaf(s8, gk, b8);
        }
    }

    // ---- nontemporal stores: write-once stream, don't evict the feature table ----
    float* opa = out + (size_t)v0 * (ODIM * FDIM) + lane;
    __builtin_nontemporal_store(a0, opa + 0*FDIM); __builtin_nontemporal_store(a1, opa + 1*FDIM);
    __builtin_nontemporal_store(a2, opa + 2*FDIM); __builtin_nontemporal_store(a3, opa + 3*FDIM);
    __builtin_nontemporal_store(a4, opa + 4*FDIM); __builtin_nontemporal_store(a5, opa + 5*FDIM);
    __builtin_nontemporal_store(a6, opa + 6*FDIM); __builtin_nontemporal_store(a7, opa + 7*FDIM);
    __builtin_nontemporal_store(a8, opa + 8*FDIM);
    float* opb = out + (size_t)(v0 + 1) * (ODIM * FDIM) + lane;
    __builtin_nontemporal_store(b0, opb + 0*FDIM); __builtin_nontemporal_store(b1, opb + 1*FDIM);
    __builtin_nontemporal_store(b2, opb + 2*FDIM); __builtin_nontemporal_store(b3, opb + 3*FDIM);
    __builtin_nontemporal_store(b4, opb + 4*FDIM); __builtin_nontemporal_store(b5, opb + 5*FDIM);
    __builtin_nontemporal_store(b6, opb + 6*FDIM); __builtin_nontemporal_store(b7, opb + 7*FDIM);
    __builtin_nontemporal_store(b8, opb + 8*FDIM);
}

extern "C" void kernel_launch(void* const* d_in, const int* in_sizes, int n_in,
                              void* d_out, int out_size, void* d_ws, size_t ws_size,
                              hipStream_t stream) {
    const float* coords = (const float*)d_in[0];   // (V,4) f32
    const float* feats  = (const float*)d_in[1];   // (V,64) f32
    // d_in[2] = distsq — unused on the inference path
    const int*   nbidx  = (const int*)d_in[3];     // (V,32) i32
    const float* lscale = (const float*)d_in[4];   // (1,) f32

    const int V = in_sizes[0] / 4;                 // 50000
    // 2 vertices per wave, 4 waves per block -> 8 vertices per block
    spcnn_kernel<<<V / 8, 256, 0, stream>>>(coords, feats, nbidx, lscale, (float*)d_out);
}